// Round 11
// baseline (1107.480 us; speedup 1.0000x reference)
//
#include <hip/hip_runtime.h>
#include <hip/hip_bf16.h>

#define NN 200000
#define EE 400000
#define HDIM 256
#define LL 4
#define FEAT 10

typedef unsigned short ushort_t;
typedef __attribute__((ext_vector_type(8))) short bf16x8;
typedef __attribute__((ext_vector_type(8))) unsigned short u16x8;
typedef __attribute__((ext_vector_type(4))) float f32x4;
typedef __attribute__((ext_vector_type(4))) unsigned int u32x4;

__device__ inline ushort_t f2bf(float f) {
    unsigned int u = __builtin_bit_cast(unsigned int, f);
    return (ushort_t)((u + 0x7fffu + ((u >> 16) & 1u)) >> 16);
}
__device__ inline float bf2f(ushort_t s) {
    unsigned int u = ((unsigned int)s) << 16;
    return __builtin_bit_cast(float, u);
}
__device__ inline float silu_f(float v) { return v / (1.0f + __expf(-v)); }

// x/U global layout PRE-SWIZZLED: row n, 16B-chunk slot s holds true chunk s ^ (n&7).

// ---------------- node init: xb = LN(silu(emb[z] + feat@Wf + bf)); 32 lanes/node
__global__ __launch_bounds__(256) void node_init_kernel(
    const int* __restrict__ z, const float* __restrict__ feat,
    const float* __restrict__ emb, const float* __restrict__ Wf,
    const float* __restrict__ bfv, const float* __restrict__ g0,
    const float* __restrict__ b0, ushort_t* __restrict__ xb)
{
    int n = blockIdx.x * 8 + (threadIdx.x >> 5);
    int nl = threadIdx.x & 31, c0 = nl * 8;
    int zi = z[n];
    float a[8];
    {
        f32x4 e0 = *(const f32x4*)&emb[(size_t)zi * HDIM + c0];
        f32x4 e1 = *(const f32x4*)&emb[(size_t)zi * HDIM + c0 + 4];
        f32x4 v0 = *(const f32x4*)&bfv[c0];
        f32x4 v1 = *(const f32x4*)&bfv[c0 + 4];
        #pragma unroll
        for (int j = 0; j < 4; ++j) { a[j] = e0[j] + v0[j]; a[4 + j] = e1[j] + v1[j]; }
    }
    #pragma unroll
    for (int f = 0; f < FEAT; ++f) {
        float sf = feat[n * FEAT + f];
        f32x4 w0 = *(const f32x4*)&Wf[f * HDIM + c0];
        f32x4 w1 = *(const f32x4*)&Wf[f * HDIM + c0 + 4];
        #pragma unroll
        for (int j = 0; j < 4; ++j) { a[j] += sf * w0[j]; a[4 + j] += sf * w1[j]; }
    }
    float s = 0.f, q = 0.f;
    #pragma unroll
    for (int c = 0; c < 8; ++c) { a[c] = silu_f(a[c]); s += a[c]; q += a[c] * a[c]; }
    #pragma unroll
    for (int o = 16; o; o >>= 1) { s += __shfl_xor(s, o, 64); q += __shfl_xor(q, o, 64); }
    float mu = s * (1.0f / HDIM);
    float var = q * (1.0f / HDIM) - mu * mu;
    float rs = rsqrtf(var + 1e-5f);
    u16x8 o8;
    #pragma unroll
    for (int c = 0; c < 8; ++c) {
        float g = g0[c0 + c], b = b0[c0 + c];
        o8[c] = f2bf((a[c] - mu) * rs * g + b);
    }
    *(u16x8*)&xb[((size_t)n << 8) + ((nl ^ (n & 7)) << 3)] = o8;
}

__global__ __launch_bounds__(256) void batch_out_kernel(
    const int* __restrict__ batch, float* __restrict__ out)
{
    int i = blockIdx.x * 256 + threadIdx.x;
    if (i < NN) out[i] = (float)batch[i];
}

// ---------------- CSR build
__global__ __launch_bounds__(256) void hist_kernel(const int* __restrict__ ei, int* __restrict__ deg)
{
    int i = blockIdx.x * 256 + threadIdx.x;
    if (i < EE) atomicAdd(&deg[ei[EE + i]], 1);
}

__global__ __launch_bounds__(256) void scan_blocks_kernel(
    const int* __restrict__ deg, int* __restrict__ off, int* __restrict__ psum)
{
    int blk = blockIdx.x, t = threadIdx.x;
    int base = blk * 1024 + t * 4;
    int v[4];
    #pragma unroll
    for (int i = 0; i < 4; ++i) v[i] = (base + i < NN) ? deg[base + i] : 0;
    int s = v[0] + v[1] + v[2] + v[3];
    int lane = t & 63, w = t >> 6;
    int ps = s;
    #pragma unroll
    for (int o = 1; o < 64; o <<= 1) { int u = __shfl_up(ps, o, 64); if (lane >= o) ps += u; }
    __shared__ int wt[4];
    if (lane == 63) wt[w] = ps;
    __syncthreads();
    int wbase = 0;
    for (int k = 0; k < w; ++k) wbase += wt[k];
    int run = wbase + ps - s;
    #pragma unroll
    for (int i = 0; i < 4; ++i) {
        if (base + i < NN) off[base + i] = run;
        run += v[i];
    }
    if (t == 255) psum[blk] = wbase + ps;
}

__global__ __launch_bounds__(256) void scan_top_kernel(int* __restrict__ psum, int nb)
{
    int t = threadIdx.x;
    int v = (t < nb) ? psum[t] : 0;
    int lane = t & 63, w = t >> 6;
    int ps = v;
    #pragma unroll
    for (int o = 1; o < 64; o <<= 1) { int u = __shfl_up(ps, o, 64); if (lane >= o) ps += u; }
    __shared__ int wt[4];
    if (lane == 63) wt[w] = ps;
    __syncthreads();
    int wbase = 0;
    for (int k = 0; k < w; ++k) wbase += wt[k];
    if (t < nb) psum[t] = wbase + ps - v;
}

__global__ __launch_bounds__(256) void scan_add_kernel(
    int* __restrict__ off, const int* __restrict__ psum, int* __restrict__ cursor)
{
    int i = blockIdx.x * 256 + threadIdx.x;
    if (i < NN) {
        int o = off[i] + psum[i >> 10];
        off[i] = o;
        cursor[i] = o;
        if (i == NN - 1) off[NN] = EE;
    }
}

__global__ __launch_bounds__(256) void scatter_kernel(
    const int* __restrict__ ei, const float* __restrict__ ea,
    int* __restrict__ cursor, int* __restrict__ srcs, float4* __restrict__ eaf)
{
    int i = blockIdx.x * 256 + threadIdx.x;
    if (i < EE) {
        int dst = ei[EE + i];
        int pos = atomicAdd(&cursor[dst], 1);
        srcs[pos] = ei[i];
        eaf[pos] = ((const float4*)ea)[i];
    }
}

// ---------------- edge MLP (layer-invariant): e16[p] = bf16(silu(eaf[p]@We + be)), CSR order
__global__ __launch_bounds__(256) void edge_mlp_kernel(
    const float4* __restrict__ eaf, const float* __restrict__ We,
    const float* __restrict__ be, ushort_t* __restrict__ e16)
{
    int p = (blockIdx.x * 256 + threadIdx.x) >> 5;
    if (p >= EE) return;
    int nl = threadIdx.x & 31, c0 = nl * 8;
    float4 av = eaf[p];
    u16x8 o8;
    #pragma unroll
    for (int j = 0; j < 8; ++j) {
        float v = be[c0 + j] + av.x * We[c0 + j] + av.y * We[HDIM + c0 + j]
                + av.z * We[2 * HDIM + c0 + j] + av.w * We[3 * HDIM + c0 + j];
        o8[j] = f2bf(silu_f(v));
    }
    *(u16x8*)&e16[((size_t)p << 8) + nl * 8] = o8;
}

// ---------------- weights: W[l][k][n] f32 -> chunk-major per-wave (8 col-waves) bf16
// Wc[l][c<8][w<8][nf<2][lane<64][e<8] = W[l][k=c*32+(lane>>4)*8+e][n=w*32+nf*16+(lane&15)]
__global__ __launch_bounds__(256) void prep_w_kernel(
    const float* __restrict__ W1, const float* __restrict__ W2,
    ushort_t* __restrict__ Wc1, ushort_t* __restrict__ Wc2)
{
    int idx = blockIdx.x * 256 + threadIdx.x;   // 2 * 4 * 65536
    int which = idx >> 18;
    int rem = idx & 0x3FFFF;
    int l = rem >> 16;
    int t = rem & 0xFFFF;
    int e = t & 7;
    int lane = (t >> 3) & 63;
    int nf = (t >> 9) & 1;
    int w8 = (t >> 10) & 7;
    int c = (t >> 13) & 7;
    int n = w8 * 32 + nf * 16 + (lane & 15);
    int k = c * 32 + (lane >> 4) * 8 + e;
    const float* W = which ? W2 : W1;
    ushort_t* Wc = which ? Wc2 : Wc1;
    Wc[rem] = f2bf(W[l * 65536 + k * 256 + n]);
}

// ---------------- aggregation: U = bf16(x_self + sum relu(x[src]+e)); 32-lane groups,
// grid-stride for load balance. USE_E=1 reads precomputed e16; USE_E=0 recomputes.
template<int USE_E>
__global__ __launch_bounds__(256) void agg_kernel(
    const int* __restrict__ off, const int* __restrict__ srcs,
    const ushort_t* __restrict__ e16, const float4* __restrict__ eaf,
    const float* __restrict__ We, const float* __restrict__ be,
    const ushort_t* __restrict__ xin, ushort_t* __restrict__ U)
{
    const int gstride = (gridDim.x * 256) >> 5;
    const int gid0 = (blockIdx.x * 256 + threadIdx.x) >> 5;
    const int nl = threadIdx.x & 31, c0 = nl * 8;
    float wv[4][8], bev[8];
    if (!USE_E) {
        #pragma unroll
        for (int r4 = 0; r4 < 4; ++r4)
            #pragma unroll
            for (int j = 0; j < 8; ++j) wv[r4][j] = We[r4 * HDIM + c0 + j];
        #pragma unroll
        for (int j = 0; j < 8; ++j) bev[j] = be[c0 + j];
    }

    for (int n = gid0; n < NN; n += gstride) {
        u16x8 xs = *(const u16x8*)&xin[((size_t)n << 8) + ((nl ^ (n & 7)) << 3)];
        float acc[8];
        #pragma unroll
        for (int j = 0; j < 8; ++j) acc[j] = bf2f(xs[j]);
        int beg = off[n], end = off[n + 1];
        if (USE_E) {
            #pragma unroll 2
            for (int p = beg; p < end; ++p) {
                int src = srcs[p];
                u16x8 xg = *(const u16x8*)&xin[((size_t)src << 8) + ((nl ^ (src & 7)) << 3)];
                u16x8 eg = *(const u16x8*)&e16[((size_t)p << 8) + nl * 8];
                #pragma unroll
                for (int j = 0; j < 8; ++j)
                    acc[j] += fmaxf(bf2f(xg[j]) + bf2f(eg[j]), 0.f);
            }
        } else {
            for (int p = beg; p < end; ++p) {
                int src = srcs[p];
                float4 av = eaf[p];
                u16x8 xg = *(const u16x8*)&xin[((size_t)src << 8) + ((nl ^ (src & 7)) << 3)];
                #pragma unroll
                for (int j = 0; j < 8; ++j) {
                    float e = silu_f(bev[j] + av.x * wv[0][j] + av.y * wv[1][j]
                                            + av.z * wv[2][j] + av.w * wv[3][j]);
                    acc[j] += fmaxf(bf2f(xg[j]) + e, 0.f);
                }
            }
        }
        u16x8 o8;
        #pragma unroll
        for (int j = 0; j < 8; ++j) o8[j] = f2bf(acc[j]);
        *(u16x8*)&U[((size_t)n << 8) + ((nl ^ (n & 7)) << 3)] = o8;
    }
}

// ---------------- MLP + LN: out = LN(xin + (silu(U@W1+b1))@W2 + b2)
// 64 rows/block, 512 thr (8 col-waves of 32 cols). Weights in registers with
// compile-time double-buffer + 1-chunk prefetch. xin residual loads HOISTED to
// kernel top (T14). Epilogue row-pass (8 thr/row, rotation swizzle). xout must
// NOT alias U when use3 (separate buffer removes in-place write amplification);
// alias fallback remains correct (blocks touch only their own rows).
template<int LAST>
__global__ __launch_bounds__(512, 4) void mlp_kernel(
    const ushort_t* U, const ushort_t* __restrict__ Wc1,
    const ushort_t* __restrict__ Wc2, const float* __restrict__ b1,
    const float* __restrict__ b2, const float* __restrict__ lng,
    const float* __restrict__ lnb, const ushort_t* __restrict__ xin,
    ushort_t* xout, float* __restrict__ xf32)
{
    __shared__ ushort_t sA[64][256];     // 32KB: U -> t -> h/v (swizzled cells)
    __shared__ float sGB[2][HDIM];       // 2KB gamma/beta
    const int tid = threadIdx.x;
    const int m0 = blockIdx.x * 64;
    const int lane = tid & 63;
    const int w = tid >> 6;
    const int lg = lane >> 4, ll = lane & 15;
    const int cb = w * 32;

    // row-pass geometry (also used for the hoisted residual loads)
    const int rr = tid >> 3, kk = tid & 7;
    const int rot = (kk + rr) & 7;
    const size_t rowb = ((size_t)(m0 + rr)) << 8;

    // ---- T14: issue xin residual loads NOW; consumed in the epilogue
    u16x8 xl[4];
    #pragma unroll
    for (int i = 0; i < 4; ++i)
        xl[i] = *(const u16x8*)&xin[rowb + ((rot + 8 * i) << 3)];

    if (tid < HDIM) sGB[0][tid] = lng[tid];
    else sGB[1][tid - HDIM] = lnb[tid - HDIM];

    float bv1[2], bv2[2];
    #pragma unroll
    for (int nf = 0; nf < 2; ++nf) {
        int c = cb + nf * 16 + ll;
        bv1[nf] = b1[c]; bv2[nf] = b2[c];
    }

    // ---- stage U tile (linear; global pre-swizzled)
    #pragma unroll
    for (int it = 0; it < 4; ++it) {
        int idx = tid + it * 512;
        *(u32x4*)((ushort_t*)sA + (idx << 3)) =
            *(const u32x4*)(U + (((size_t)m0) << 8) + (idx << 3));
    }
    __syncthreads();

    f32x4 acc[4][2] = {};
    const ushort_t* wp1 = Wc1 + w * 1024 + lane * 8;
    const ushort_t* wp2 = Wc2 + w * 1024 + lane * 8;
    bf16x8 wbuf[2][2];
    wbuf[0][0] = *(const bf16x8*)(wp1);
    wbuf[0][1] = *(const bf16x8*)(wp1 + 512);

    // ---- GEMM1 (reg prefetch; last iter prefetches W2 chunk0)
    #pragma unroll
    for (int p = 0; p < 8; ++p) {
        const ushort_t* nsrc = (p < 7) ? (wp1 + (p + 1) * 8192) : wp2;
        wbuf[(p + 1) & 1][0] = *(const bf16x8*)(nsrc);
        wbuf[(p + 1) & 1][1] = *(const bf16x8*)(nsrc + 512);
        bf16x8 af[4];
        #pragma unroll
        for (int m = 0; m < 4; ++m) {
            int r = m * 16 + ll;
            af[m] = *(const bf16x8*)&sA[r][(((p * 4 + lg) ^ (r & 7)) << 3)];
        }
        #pragma unroll
        for (int m = 0; m < 4; ++m)
            #pragma unroll
            for (int nf = 0; nf < 2; ++nf)
                acc[m][nf] = __builtin_amdgcn_mfma_f32_16x16x32_bf16(
                    af[m], wbuf[p & 1][nf], acc[m][nf], 0, 0, 0);
    }
    __syncthreads();   // all waves done reading sA(U)

    // ---- t = silu(acc + b1) -> sA; reset acc
    #pragma unroll
    for (int m = 0; m < 4; ++m)
        #pragma unroll
        for (int nf = 0; nf < 2; ++nf)
            #pragma unroll
            for (int j = 0; j < 4; ++j) {
                int r = m * 16 + lg * 4 + j;
                int c = cb + nf * 16 + ll;
                sA[r][((((c >> 3) ^ (r & 7)) << 3) | (c & 7))] =
                    f2bf(silu_f(acc[m][nf][j] + bv1[nf]));
                acc[m][nf][j] = 0.f;
            }
    __syncthreads();   // t visible

    // ---- GEMM2
    #pragma unroll
    for (int p = 0; p < 8; ++p) {
        if (p < 7) {
            wbuf[(p + 1) & 1][0] = *(const bf16x8*)(wp2 + (p + 1) * 8192);
            wbuf[(p + 1) & 1][1] = *(const bf16x8*)(wp2 + (p + 1) * 8192 + 512);
        }
        bf16x8 af[4];
        #pragma unroll
        for (int m = 0; m < 4; ++m) {
            int r = m * 16 + ll;
            af[m] = *(const bf16x8*)&sA[r][(((p * 4 + lg) ^ (r & 7)) << 3)];
        }
        #pragma unroll
        for (int m = 0; m < 4; ++m)
            #pragma unroll
            for (int nf = 0; nf < 2; ++nf)
                acc[m][nf] = __builtin_amdgcn_mfma_f32_16x16x32_bf16(
                    af[m], wbuf[p & 1][nf], acc[m][nf], 0, 0, 0);
    }
    __syncthreads();   // all waves done reading sA(t)

    // ---- h = acc + b2 -> sA cells (bf16)
    #pragma unroll
    for (int m = 0; m < 4; ++m)
        #pragma unroll
        for (int nf = 0; nf < 2; ++nf)
            #pragma unroll
            for (int j = 0; j < 4; ++j) {
                int r = m * 16 + lg * 4 + j;
                int c = cb + nf * 16 + ll;
                sA[r][((((c >> 3) ^ (r & 7)) << 3) | (c & 7))] =
                    f2bf(acc[m][nf][j] + bv2[nf]);
            }
    __syncthreads();   // h visible

    // ---- row-pass LN: 8 thr/row, rotation swizzle; residual from hoisted regs
    {
        float s = 0.f, q = 0.f;
        #pragma unroll
        for (int i = 0; i < 4; ++i) {
            int slot = rot + 8 * i;
            u16x8 h8 = *(const u16x8*)&sA[rr][slot << 3];
            u16x8 v8;
            #pragma unroll
            for (int j = 0; j < 8; ++j) {
                float v = bf2f(h8[j]) + bf2f(xl[i][j]);
                s += v; q += v * v;
                v8[j] = f2bf(v);
            }
            *(u16x8*)&sA[rr][slot << 3] = v8;   // own cells; no cross-thread hazard
        }
        #pragma unroll
        for (int o = 1; o < 8; o <<= 1) {
            s += __shfl_xor(s, o, 64);
            q += __shfl_xor(q, o, 64);
        }
        float mu = s * (1.0f / HDIM);
        float var = q * (1.0f / HDIM) - mu * mu;
        float rs = rsqrtf(var + 1e-5f);
        #pragma unroll
        for (int i = 0; i < 4; ++i) {
            int slot = rot + 8 * i;
            int chunk = slot ^ (rr & 7);        // true cols chunk*8..+7
            u16x8 v8 = *(const u16x8*)&sA[rr][slot << 3];
            if (LAST) {
                float* xrow = xf32 + (((size_t)(m0 + rr)) << 8);
                f32x4 o0, o1;
                #pragma unroll
                for (int j = 0; j < 4; ++j) {
                    o0[j] = (bf2f(v8[j]) - mu) * rs * sGB[0][chunk * 8 + j]
                            + sGB[1][chunk * 8 + j];
                    o1[j] = (bf2f(v8[4 + j]) - mu) * rs * sGB[0][chunk * 8 + 4 + j]
                            + sGB[1][chunk * 8 + 4 + j];
                }
                *(f32x4*)&xrow[chunk * 8] = o0;
                *(f32x4*)&xrow[chunk * 8 + 4] = o1;
            } else {
                u16x8 o8;
                #pragma unroll
                for (int j = 0; j < 8; ++j)
                    o8[j] = f2bf((bf2f(v8[j]) - mu) * rs * sGB[0][chunk * 8 + j]
                                 + sGB[1][chunk * 8 + j]);
                *(u16x8*)&xout[rowb + (slot << 3)] = o8;
            }
        }
    }
}

extern "C" void kernel_launch(void* const* d_in, const int* in_sizes, int n_in,
                              void* d_out, int out_size, void* d_ws, size_t ws_size,
                              hipStream_t stream)
{
    const int*   z    = (const int*)d_in[0];
    const float* feat = (const float*)d_in[1];
    const int*   ei   = (const int*)d_in[2];
    const float* ea   = (const float*)d_in[3];
    const int*   batch= (const int*)d_in[4];
    const float* emb  = (const float*)d_in[5];
    const float* Wf   = (const float*)d_in[6];
    const float* bfv  = (const float*)d_in[7];
    const float* g0   = (const float*)d_in[8];
    const float* b0   = (const float*)d_in[9];
    const float* We   = (const float*)d_in[10];
    const float* be   = (const float*)d_in[11];
    const float* W1   = (const float*)d_in[12];
    const float* b1   = (const float*)d_in[13];
    const float* W2   = (const float*)d_in[14];
    const float* b2   = (const float*)d_in[15];
    const float* lng  = (const float*)d_in[16];
    const float* lnb  = (const float*)d_in[17];

    float* x    = (float*)d_out;
    float* outb = (float*)d_out + (size_t)NN * HDIM;

    char* ws = (char*)d_ws;
    ushort_t* xb0  = (ushort_t*)ws;                         // 102,400,000 B
    ushort_t* xb1  = (ushort_t*)(ws + 102400000);           // 102,400,000 B
    float4*   eaf  = (float4*)(ws + 204800000);             // 6,400,000 B
    int*      srcs = (int*)(ws + 211200000);                // 1,600,000 B
    int*      off  = (int*)(ws + 212800000);                // 800,016 B
    int*      cursor = (int*)(ws + 213600016);              // 800,000 B
    int*      deg  = (int*)(ws + 214400016);                // 800,000 B
    int*      psum = (int*)(ws + 215200016);                // 1,008 B
    ushort_t* Wc1  = (ushort_t*)(ws + 215201024);           // 524,288 B
    ushort_t* Wc2  = (ushort_t*)(ws + 215725312);           // 524,288 B
    ushort_t* e16  = (ushort_t*)(ws + 216249600);           // 204,800,000 B (optional)
    ushort_t* xb2  = (ushort_t*)(ws + 421049600);           // 102,400,000 B (optional)
    const int use_e = (ws_size >= (size_t)421049600) ? 1 : 0;
    const int use3  = (ws_size >= (size_t)523449600) ? 1 : 0;

    prep_w_kernel<<<2048, 256, 0, stream>>>(W1, W2, Wc1, Wc2);
    batch_out_kernel<<<782, 256, 0, stream>>>(batch, outb);
    node_init_kernel<<<NN / 8, 256, 0, stream>>>(z, feat, emb, Wf, bfv, g0, b0, xb0);

    hipMemsetAsync(deg, 0, NN * sizeof(int), stream);
    hist_kernel<<<1563, 256, 0, stream>>>(ei, deg);
    scan_blocks_kernel<<<196, 256, 0, stream>>>(deg, off, psum);
    scan_top_kernel<<<1, 256, 0, stream>>>(psum, 196);
    scan_add_kernel<<<782, 256, 0, stream>>>(off, psum, cursor);
    scatter_kernel<<<1563, 256, 0, stream>>>(ei, ea, cursor, srcs, eaf);
    if (use_e)
        edge_mlp_kernel<<<EE / 8, 256, 0, stream>>>(eaf, We, be, e16);

    // buffer rotation: xin -> (agg) U -> (mlp) out. With use3, out is a third
    // buffer (no aliasing); else out aliases U (blocks touch only their own rows).
    ushort_t* bufs[3] = {xb0, xb1, xb2};
    int xi = 0;
    for (int l = 0; l < LL; ++l) {
        ushort_t* xin = bufs[xi];
        int ui = use3 ? (xi + 1) % 3 : (xi ^ 1);
        int oi = use3 ? (xi + 2) % 3 : ui;
        ushort_t* Ub = bufs[ui];
        ushort_t* Ob = bufs[oi];
        if (use_e)
            agg_kernel<1><<<2048, 256, 0, stream>>>(off, srcs, e16, eaf, We, be, xin, Ub);
        else
            agg_kernel<0><<<2048, 256, 0, stream>>>(off, srcs, e16, eaf, We, be, xin, Ub);
        if (l == LL - 1) {
            mlp_kernel<1><<<NN / 64, 512, 0, stream>>>(
                Ub, Wc1 + l * 65536, Wc2 + l * 65536, b1 + l * HDIM, b2 + l * HDIM,
                lng + l * HDIM, lnb + l * HDIM, xin, Ob, x);
        } else {
            mlp_kernel<0><<<NN / 64, 512, 0, stream>>>(
                Ub, Wc1 + l * 65536, Wc2 + l * 65536, b1 + l * HDIM, b2 + l * HDIM,
                lng + l * HDIM, lnb + l * HDIM, xin, Ob, nullptr);
        }
        xi = oi;
    }
}

// Round 12
// 998.617 us; speedup vs baseline: 1.1090x; 1.1090x over previous
//
#include <hip/hip_runtime.h>
#include <hip/hip_bf16.h>

#define NN 200000
#define EE 400000
#define HDIM 256
#define LL 4
#define FEAT 10

#if defined(__has_builtin)
#if __has_builtin(__builtin_amdgcn_cvt_pk_fp8_f32) && __has_builtin(__builtin_amdgcn_cvt_pk_f32_fp8)
#define HAVE_FP8 1
#endif
#endif
#ifndef HAVE_FP8
#define HAVE_FP8 0
#endif

typedef unsigned short ushort_t;
typedef __attribute__((ext_vector_type(8))) short bf16x8;
typedef __attribute__((ext_vector_type(8))) unsigned short u16x8;
typedef __attribute__((ext_vector_type(2))) float f32x2;
typedef __attribute__((ext_vector_type(4))) float f32x4;
typedef __attribute__((ext_vector_type(4))) unsigned int u32x4;

__device__ inline ushort_t f2bf(float f) {
    unsigned int u = __builtin_bit_cast(unsigned int, f);
    return (ushort_t)((u + 0x7fffu + ((u >> 16) & 1u)) >> 16);
}
__device__ inline float bf2f(ushort_t s) {
    unsigned int u = ((unsigned int)s) << 16;
    return __builtin_bit_cast(float, u);
}
__device__ inline float silu_f(float v) { return v / (1.0f + __expf(-v)); }

// x/U global layout PRE-SWIZZLED: row n, 16B-chunk slot s holds true chunk s ^ (n&7).

// ---------------- node init: xb = LN(silu(emb[z] + feat@Wf + bf)); 32 lanes/node
__global__ __launch_bounds__(256) void node_init_kernel(
    const int* __restrict__ z, const float* __restrict__ feat,
    const float* __restrict__ emb, const float* __restrict__ Wf,
    const float* __restrict__ bfv, const float* __restrict__ g0,
    const float* __restrict__ b0, ushort_t* __restrict__ xb)
{
    int n = blockIdx.x * 8 + (threadIdx.x >> 5);
    int nl = threadIdx.x & 31, c0 = nl * 8;
    int zi = z[n];
    float a[8];
    {
        f32x4 e0 = *(const f32x4*)&emb[(size_t)zi * HDIM + c0];
        f32x4 e1 = *(const f32x4*)&emb[(size_t)zi * HDIM + c0 + 4];
        f32x4 v0 = *(const f32x4*)&bfv[c0];
        f32x4 v1 = *(const f32x4*)&bfv[c0 + 4];
        #pragma unroll
        for (int j = 0; j < 4; ++j) { a[j] = e0[j] + v0[j]; a[4 + j] = e1[j] + v1[j]; }
    }
    #pragma unroll
    for (int f = 0; f < FEAT; ++f) {
        float sf = feat[n * FEAT + f];
        f32x4 w0 = *(const f32x4*)&Wf[f * HDIM + c0];
        f32x4 w1 = *(const f32x4*)&Wf[f * HDIM + c0 + 4];
        #pragma unroll
        for (int j = 0; j < 4; ++j) { a[j] += sf * w0[j]; a[4 + j] += sf * w1[j]; }
    }
    float s = 0.f, q = 0.f;
    #pragma unroll
    for (int c = 0; c < 8; ++c) { a[c] = silu_f(a[c]); s += a[c]; q += a[c] * a[c]; }
    #pragma unroll
    for (int o = 16; o; o >>= 1) { s += __shfl_xor(s, o, 64); q += __shfl_xor(q, o, 64); }
    float mu = s * (1.0f / HDIM);
    float var = q * (1.0f / HDIM) - mu * mu;
    float rs = rsqrtf(var + 1e-5f);
    u16x8 o8;
    #pragma unroll
    for (int c = 0; c < 8; ++c) {
        float g = g0[c0 + c], b = b0[c0 + c];
        o8[c] = f2bf((a[c] - mu) * rs * g + b);
    }
    *(u16x8*)&xb[((size_t)n << 8) + ((nl ^ (n & 7)) << 3)] = o8;
}

__global__ __launch_bounds__(256) void batch_out_kernel(
    const int* __restrict__ batch, float* __restrict__ out)
{
    int i = blockIdx.x * 256 + threadIdx.x;
    if (i < NN) out[i] = (float)batch[i];
}

// ---------------- CSR build
__global__ __launch_bounds__(256) void hist_kernel(const int* __restrict__ ei, int* __restrict__ deg)
{
    int i = blockIdx.x * 256 + threadIdx.x;
    if (i < EE) atomicAdd(&deg[ei[EE + i]], 1);
}

__global__ __launch_bounds__(256) void scan_blocks_kernel(
    const int* __restrict__ deg, int* __restrict__ off, int* __restrict__ psum)
{
    int blk = blockIdx.x, t = threadIdx.x;
    int base = blk * 1024 + t * 4;
    int v[4];
    #pragma unroll
    for (int i = 0; i < 4; ++i) v[i] = (base + i < NN) ? deg[base + i] : 0;
    int s = v[0] + v[1] + v[2] + v[3];
    int lane = t & 63, w = t >> 6;
    int ps = s;
    #pragma unroll
    for (int o = 1; o < 64; o <<= 1) { int u = __shfl_up(ps, o, 64); if (lane >= o) ps += u; }
    __shared__ int wt[4];
    if (lane == 63) wt[w] = ps;
    __syncthreads();
    int wbase = 0;
    for (int k = 0; k < w; ++k) wbase += wt[k];
    int run = wbase + ps - s;
    #pragma unroll
    for (int i = 0; i < 4; ++i) {
        if (base + i < NN) off[base + i] = run;
        run += v[i];
    }
    if (t == 255) psum[blk] = wbase + ps;
}

__global__ __launch_bounds__(256) void scan_top_kernel(int* __restrict__ psum, int nb)
{
    int t = threadIdx.x;
    int v = (t < nb) ? psum[t] : 0;
    int lane = t & 63, w = t >> 6;
    int ps = v;
    #pragma unroll
    for (int o = 1; o < 64; o <<= 1) { int u = __shfl_up(ps, o, 64); if (lane >= o) ps += u; }
    __shared__ int wt[4];
    if (lane == 63) wt[w] = ps;
    __syncthreads();
    int wbase = 0;
    for (int k = 0; k < w; ++k) wbase += wt[k];
    if (t < nb) psum[t] = wbase + ps - v;
}

__global__ __launch_bounds__(256) void scan_add_kernel(
    int* __restrict__ off, const int* __restrict__ psum, int* __restrict__ cursor)
{
    int i = blockIdx.x * 256 + threadIdx.x;
    if (i < NN) {
        int o = off[i] + psum[i >> 10];
        off[i] = o;
        cursor[i] = o;
        if (i == NN - 1) off[NN] = EE;
    }
}

__global__ __launch_bounds__(256) void scatter_kernel(
    const int* __restrict__ ei, const float* __restrict__ ea,
    int* __restrict__ cursor, int* __restrict__ srcs, float4* __restrict__ eaf)
{
    int i = blockIdx.x * 256 + threadIdx.x;
    if (i < EE) {
        int dst = ei[EE + i];
        int pos = atomicAdd(&cursor[dst], 1);
        srcs[pos] = ei[i];
        eaf[pos] = ((const float4*)ea)[i];
    }
}

// ---------------- edge MLP (layer-invariant): e = silu(eaf@We + be), CSR order.
// fp8 (8B/lane) when available, else bf16 (16B/lane).
__global__ __launch_bounds__(256) void edge_mlp_kernel(
    const float4* __restrict__ eaf, const float* __restrict__ We,
    const float* __restrict__ be, void* __restrict__ eout)
{
    int p = (blockIdx.x * 256 + threadIdx.x) >> 5;
    if (p >= EE) return;
    int nl = threadIdx.x & 31, c0 = nl * 8;
    float4 av = eaf[p];
    float v[8];
    #pragma unroll
    for (int j = 0; j < 8; ++j) {
        float t = be[c0 + j] + av.x * We[c0 + j] + av.y * We[HDIM + c0 + j]
                + av.z * We[2 * HDIM + c0 + j] + av.w * We[3 * HDIM + c0 + j];
        v[j] = silu_f(t);
    }
#if HAVE_FP8
    int t0 = __builtin_amdgcn_cvt_pk_fp8_f32(v[0], v[1], 0, false);
    t0 = __builtin_amdgcn_cvt_pk_fp8_f32(v[2], v[3], t0, true);
    int t1 = __builtin_amdgcn_cvt_pk_fp8_f32(v[4], v[5], 0, false);
    t1 = __builtin_amdgcn_cvt_pk_fp8_f32(v[6], v[7], t1, true);
    uint2 o;
    o.x = (unsigned int)t0;
    o.y = (unsigned int)t1;
    ((uint2*)eout)[(size_t)p * 32 + nl] = o;
#else
    u16x8 o8;
    #pragma unroll
    for (int j = 0; j < 8; ++j) o8[j] = f2bf(v[j]);
    *(u16x8*)&((ushort_t*)eout)[((size_t)p << 8) + nl * 8] = o8;
#endif
}

// ---------------- weights: W[l][k][n] f32 -> chunk-major per-wave (8 col-waves) bf16
// Wc[l][c<8][w<8][nf<2][lane<64][e<8] = W[l][k=c*32+(lane>>4)*8+e][n=w*32+nf*16+(lane&15)]
// (this per-lane map serves as the MFMA A-operand fragment: row=lane&15, k=(lane>>4)*8+e)
__global__ __launch_bounds__(256) void prep_w_kernel(
    const float* __restrict__ W1, const float* __restrict__ W2,
    ushort_t* __restrict__ Wc1, ushort_t* __restrict__ Wc2)
{
    int idx = blockIdx.x * 256 + threadIdx.x;   // 2 * 4 * 65536
    int which = idx >> 18;
    int rem = idx & 0x3FFFF;
    int l = rem >> 16;
    int t = rem & 0xFFFF;
    int e = t & 7;
    int lane = (t >> 3) & 63;
    int nf = (t >> 9) & 1;
    int w8 = (t >> 10) & 7;
    int c = (t >> 13) & 7;
    int n = w8 * 32 + nf * 16 + (lane & 15);
    int k = c * 32 + (lane >> 4) * 8 + e;
    const float* W = which ? W2 : W1;
    ushort_t* Wc = which ? Wc2 : Wc1;
    Wc[rem] = f2bf(W[l * 65536 + k * 256 + n]);
}

// ---------------- aggregation: U = bf16(x_self + sum relu(x[src]+e)); 32-lane groups,
// grid-stride. USE_E=1 reads precomputed e (fp8 or bf16); USE_E=0 recomputes.
template<int USE_E>
__global__ __launch_bounds__(256) void agg_kernel(
    const int* __restrict__ off, const int* __restrict__ srcs,
    const void* __restrict__ eprec, const float4* __restrict__ eaf,
    const float* __restrict__ We, const float* __restrict__ be,
    const ushort_t* __restrict__ xin, ushort_t* __restrict__ U)
{
    const int gstride = (gridDim.x * 256) >> 5;
    const int gid0 = (blockIdx.x * 256 + threadIdx.x) >> 5;
    const int nl = threadIdx.x & 31, c0 = nl * 8;
    float wv[4][8], bev[8];
    if (!USE_E) {
        #pragma unroll
        for (int r4 = 0; r4 < 4; ++r4)
            #pragma unroll
            for (int j = 0; j < 8; ++j) wv[r4][j] = We[r4 * HDIM + c0 + j];
        #pragma unroll
        for (int j = 0; j < 8; ++j) bev[j] = be[c0 + j];
    }

    for (int n = gid0; n < NN; n += gstride) {
        u16x8 xs = *(const u16x8*)&xin[((size_t)n << 8) + ((nl ^ (n & 7)) << 3)];
        float acc[8];
        #pragma unroll
        for (int j = 0; j < 8; ++j) acc[j] = bf2f(xs[j]);
        int beg = off[n], end = off[n + 1];
        if (USE_E) {
            for (int p = beg; p < end; ++p) {
                int src = srcs[p];
                u16x8 xg = *(const u16x8*)&xin[((size_t)src << 8) + ((nl ^ (src & 7)) << 3)];
#if HAVE_FP8
                uint2 eg = ((const uint2*)eprec)[(size_t)p * 32 + nl];
                f32x2 e01 = __builtin_amdgcn_cvt_pk_f32_fp8((int)eg.x, false);
                f32x2 e23 = __builtin_amdgcn_cvt_pk_f32_fp8((int)eg.x, true);
                f32x2 e45 = __builtin_amdgcn_cvt_pk_f32_fp8((int)eg.y, false);
                f32x2 e67 = __builtin_amdgcn_cvt_pk_f32_fp8((int)eg.y, true);
                float ev[8] = {e01[0], e01[1], e23[0], e23[1],
                               e45[0], e45[1], e67[0], e67[1]};
#else
                u16x8 eg = *(const u16x8*)&((const ushort_t*)eprec)[((size_t)p << 8) + nl * 8];
                float ev[8];
                #pragma unroll
                for (int j = 0; j < 8; ++j) ev[j] = bf2f(eg[j]);
#endif
                #pragma unroll
                for (int j = 0; j < 8; ++j)
                    acc[j] += fmaxf(bf2f(xg[j]) + ev[j], 0.f);
            }
        } else {
            for (int p = beg; p < end; ++p) {
                int src = srcs[p];
                float4 av = eaf[p];
                u16x8 xg = *(const u16x8*)&xin[((size_t)src << 8) + ((nl ^ (src & 7)) << 3)];
                #pragma unroll
                for (int j = 0; j < 8; ++j) {
                    float e = silu_f(bev[j] + av.x * wv[0][j] + av.y * wv[1][j]
                                            + av.z * wv[2][j] + av.w * wv[3][j]);
                    acc[j] += fmaxf(bf2f(xg[j]) + e, 0.f);
                }
            }
        }
        u16x8 o8;
        #pragma unroll
        for (int j = 0; j < 8; ++j) o8[j] = f2bf(acc[j]);
        *(u16x8*)&U[((size_t)n << 8) + ((nl ^ (n & 7)) << 3)] = o8;
    }
}

// ---------------- MLP + LN: out = LN(xin + (silu(U@W1+b1))@W2 + b2)
// 64 rows/block, 512 thr (8 col-waves of 32 cols). Weights in registers (dbuf +
// 1-chunk prefetch) used as the MFMA *A* operand: D row = weight-n (lg*4+j),
// D col = U-row (lane&15) -> each thread's 4 acc values are 4 CONSECUTIVE cols of
// one row => t/h phases are aligned ds_write_b64 (conflict-light). Epilogue
// row-pass (8 thr/row, rotation swizzle). xout aliases U (own rows only).
template<int LAST>
__global__ __launch_bounds__(512, 4) void mlp_kernel(
    const ushort_t* U, const ushort_t* __restrict__ Wc1,
    const ushort_t* __restrict__ Wc2, const float* __restrict__ b1,
    const float* __restrict__ b2, const float* __restrict__ lng,
    const float* __restrict__ lnb, const ushort_t* __restrict__ xin,
    ushort_t* xout, float* __restrict__ xf32)
{
    __shared__ ushort_t sA[64][256];     // 32KB: U -> t -> h/v (swizzled cells)
    __shared__ float sGB[2][HDIM];       // 2KB gamma/beta
    const int tid = threadIdx.x;
    const int m0 = blockIdx.x * 64;
    const int lane = tid & 63;
    const int w = tid >> 6;
    const int lg = lane >> 4, ll = lane & 15;
    const int cb = w * 32;

    if (tid < HDIM) sGB[0][tid] = lng[tid];
    else sGB[1][tid - HDIM] = lnb[tid - HDIM];

    // bias vectors over n = cb + nf*16 + lg*4 + j  (4 consecutive)
    f32x4 bv1v[2], bv2v[2];
    #pragma unroll
    for (int nf = 0; nf < 2; ++nf) {
        int nb = cb + nf * 16 + lg * 4;
        bv1v[nf] = *(const f32x4*)&b1[nb];
        bv2v[nf] = *(const f32x4*)&b2[nb];
    }

    // ---- stage U tile (linear; global pre-swizzled)
    #pragma unroll
    for (int it = 0; it < 4; ++it) {
        int idx = tid + it * 512;
        *(u32x4*)((ushort_t*)sA + (idx << 3)) =
            *(const u32x4*)(U + (((size_t)m0) << 8) + (idx << 3));
    }
    __syncthreads();

    f32x4 acc[4][2] = {};
    const ushort_t* wp1 = Wc1 + w * 1024 + lane * 8;
    const ushort_t* wp2 = Wc2 + w * 1024 + lane * 8;
    bf16x8 wbuf[2][2];
    wbuf[0][0] = *(const bf16x8*)(wp1);
    wbuf[0][1] = *(const bf16x8*)(wp1 + 512);

    // ---- GEMM1 (reg prefetch; last iter prefetches W2 chunk0); W as A-operand
    #pragma unroll
    for (int p = 0; p < 8; ++p) {
        const ushort_t* nsrc = (p < 7) ? (wp1 + (p + 1) * 8192) : wp2;
        wbuf[(p + 1) & 1][0] = *(const bf16x8*)(nsrc);
        wbuf[(p + 1) & 1][1] = *(const bf16x8*)(nsrc + 512);
        bf16x8 af[4];
        #pragma unroll
        for (int m = 0; m < 4; ++m) {
            int r = m * 16 + ll;
            af[m] = *(const bf16x8*)&sA[r][(((p * 4 + lg) ^ (r & 7)) << 3)];
        }
        #pragma unroll
        for (int m = 0; m < 4; ++m)
            #pragma unroll
            for (int nf = 0; nf < 2; ++nf)
                acc[m][nf] = __builtin_amdgcn_mfma_f32_16x16x32_bf16(
                    wbuf[p & 1][nf], af[m], acc[m][nf], 0, 0, 0);
    }
    __syncthreads();   // all waves done reading sA(U)

    // ---- t = silu(acc + b1) -> sA via ds_write_b64; reset acc
    #pragma unroll
    for (int m = 0; m < 4; ++m) {
        int r = m * 16 + ll, rx = r & 7;
        #pragma unroll
        for (int nf = 0; nf < 2; ++nf) {
            int chunk = ((cb + nf * 16) >> 3) + (lg >> 1);
            int celloff = ((chunk ^ rx) << 3) + (lg & 1) * 4;
            ushort4 o;
            o.x = f2bf(silu_f(acc[m][nf][0] + bv1v[nf][0]));
            o.y = f2bf(silu_f(acc[m][nf][1] + bv1v[nf][1]));
            o.z = f2bf(silu_f(acc[m][nf][2] + bv1v[nf][2]));
            o.w = f2bf(silu_f(acc[m][nf][3] + bv1v[nf][3]));
            *(ushort4*)&sA[r][celloff] = o;
            acc[m][nf][0] = 0.f; acc[m][nf][1] = 0.f;
            acc[m][nf][2] = 0.f; acc[m][nf][3] = 0.f;
        }
    }
    __syncthreads();   // t visible

    // ---- GEMM2
    #pragma unroll
    for (int p = 0; p < 8; ++p) {
        if (p < 7) {
            wbuf[(p + 1) & 1][0] = *(const bf16x8*)(wp2 + (p + 1) * 8192);
            wbuf[(p + 1) & 1][1] = *(const bf16x8*)(wp2 + (p + 1) * 8192 + 512);
        }
        bf16x8 af[4];
        #pragma unroll
        for (int m = 0; m < 4; ++m) {
            int r = m * 16 + ll;
            af[m] = *(const bf16x8*)&sA[r][(((p * 4 + lg) ^ (r & 7)) << 3)];
        }
        #pragma unroll
        for (int m = 0; m < 4; ++m)
            #pragma unroll
            for (int nf = 0; nf < 2; ++nf)
                acc[m][nf] = __builtin_amdgcn_mfma_f32_16x16x32_bf16(
                    wbuf[p & 1][nf], af[m], acc[m][nf], 0, 0, 0);
    }
    __syncthreads();   // all waves done reading sA(t)

    // ---- h = acc + b2 -> sA cells (ds_write_b64)
    #pragma unroll
    for (int m = 0; m < 4; ++m) {
        int r = m * 16 + ll, rx = r & 7;
        #pragma unroll
        for (int nf = 0; nf < 2; ++nf) {
            int chunk = ((cb + nf * 16) >> 3) + (lg >> 1);
            int celloff = ((chunk ^ rx) << 3) + (lg & 1) * 4;
            ushort4 o;
            o.x = f2bf(acc[m][nf][0] + bv2v[nf][0]);
            o.y = f2bf(acc[m][nf][1] + bv2v[nf][1]);
            o.z = f2bf(acc[m][nf][2] + bv2v[nf][2]);
            o.w = f2bf(acc[m][nf][3] + bv2v[nf][3]);
            *(ushort4*)&sA[r][celloff] = o;
        }
    }
    __syncthreads();   // h visible

    // ---- row-pass LN: 8 thr/row, rotation swizzle; x residual from global (L2/L3-hot)
    {
        int rr = tid >> 3, kk = tid & 7;
        int rot = (kk + rr) & 7;
        size_t rowb = ((size_t)(m0 + rr)) << 8;
        float s = 0.f, q = 0.f;
        #pragma unroll
        for (int i = 0; i < 4; ++i) {
            int slot = rot + 8 * i;
            u16x8 h8 = *(const u16x8*)&sA[rr][slot << 3];
            u16x8 x8 = *(const u16x8*)&xin[rowb + (slot << 3)];
            u16x8 v8;
            #pragma unroll
            for (int j = 0; j < 8; ++j) {
                float v = bf2f(h8[j]) + bf2f(x8[j]);
                s += v; q += v * v;
                v8[j] = f2bf(v);
            }
            *(u16x8*)&sA[rr][slot << 3] = v8;   // own cells; no cross-thread hazard
        }
        #pragma unroll
        for (int o = 1; o < 8; o <<= 1) {
            s += __shfl_xor(s, o, 64);
            q += __shfl_xor(q, o, 64);
        }
        float mu = s * (1.0f / HDIM);
        float var = q * (1.0f / HDIM) - mu * mu;
        float rs = rsqrtf(var + 1e-5f);
        #pragma unroll
        for (int i = 0; i < 4; ++i) {
            int slot = rot + 8 * i;
            int chunk = slot ^ (rr & 7);        // true cols chunk*8..+7
            u16x8 v8 = *(const u16x8*)&sA[rr][slot << 3];
            if (LAST) {
                float* xrow = xf32 + (((size_t)(m0 + rr)) << 8);
                f32x4 o0, o1;
                #pragma unroll
                for (int j = 0; j < 4; ++j) {
                    o0[j] = (bf2f(v8[j]) - mu) * rs * sGB[0][chunk * 8 + j]
                            + sGB[1][chunk * 8 + j];
                    o1[j] = (bf2f(v8[4 + j]) - mu) * rs * sGB[0][chunk * 8 + 4 + j]
                            + sGB[1][chunk * 8 + 4 + j];
                }
                *(f32x4*)&xrow[chunk * 8] = o0;
                *(f32x4*)&xrow[chunk * 8 + 4] = o1;
            } else {
                u16x8 o8;
                #pragma unroll
                for (int j = 0; j < 8; ++j)
                    o8[j] = f2bf((bf2f(v8[j]) - mu) * rs * sGB[0][chunk * 8 + j]
                                 + sGB[1][chunk * 8 + j]);
                *(u16x8*)&xout[rowb + (slot << 3)] = o8;
            }
        }
    }
}

extern "C" void kernel_launch(void* const* d_in, const int* in_sizes, int n_in,
                              void* d_out, int out_size, void* d_ws, size_t ws_size,
                              hipStream_t stream)
{
    const int*   z    = (const int*)d_in[0];
    const float* feat = (const float*)d_in[1];
    const int*   ei   = (const int*)d_in[2];
    const float* ea   = (const float*)d_in[3];
    const int*   batch= (const int*)d_in[4];
    const float* emb  = (const float*)d_in[5];
    const float* Wf   = (const float*)d_in[6];
    const float* bfv  = (const float*)d_in[7];
    const float* g0   = (const float*)d_in[8];
    const float* b0   = (const float*)d_in[9];
    const float* We   = (const float*)d_in[10];
    const float* be   = (const float*)d_in[11];
    const float* W1   = (const float*)d_in[12];
    const float* b1   = (const float*)d_in[13];
    const float* W2   = (const float*)d_in[14];
    const float* b2   = (const float*)d_in[15];
    const float* lng  = (const float*)d_in[16];
    const float* lnb  = (const float*)d_in[17];

    float* x    = (float*)d_out;
    float* outb = (float*)d_out + (size_t)NN * HDIM;

    char* ws = (char*)d_ws;
    ushort_t* xb0  = (ushort_t*)ws;                         // 102,400,000 B
    ushort_t* xb1  = (ushort_t*)(ws + 102400000);           // 102,400,000 B
    float4*   eaf  = (float4*)(ws + 204800000);             // 6,400,000 B
    int*      srcs = (int*)(ws + 211200000);                // 1,600,000 B
    int*      off  = (int*)(ws + 212800000);                // 800,016 B
    int*      cursor = (int*)(ws + 213600016);              // 800,000 B
    int*      deg  = (int*)(ws + 214400016);                // 800,000 B
    int*      psum = (int*)(ws + 215200016);                // 1,008 B
    ushort_t* Wc1  = (ushort_t*)(ws + 215201024);           // 524,288 B
    ushort_t* Wc2  = (ushort_t*)(ws + 215725312);           // 524,288 B
    void*     eprec= (void*)(ws + 216249600);               // fp8: 102.4MB / bf16: 204.8MB
#if HAVE_FP8
    const size_t eneed = (size_t)216249600 + (size_t)EE * 256;
#else
    const size_t eneed = (size_t)216249600 + (size_t)EE * 512;
#endif
    const int use_e = (ws_size >= eneed) ? 1 : 0;

    prep_w_kernel<<<2048, 256, 0, stream>>>(W1, W2, Wc1, Wc2);
    batch_out_kernel<<<782, 256, 0, stream>>>(batch, outb);
    node_init_kernel<<<NN / 8, 256, 0, stream>>>(z, feat, emb, Wf, bfv, g0, b0, xb0);

    hipMemsetAsync(deg, 0, NN * sizeof(int), stream);
    hist_kernel<<<1563, 256, 0, stream>>>(ei, deg);
    scan_blocks_kernel<<<196, 256, 0, stream>>>(deg, off, psum);
    scan_top_kernel<<<1, 256, 0, stream>>>(psum, 196);
    scan_add_kernel<<<782, 256, 0, stream>>>(off, psum, cursor);
    scatter_kernel<<<1563, 256, 0, stream>>>(ei, ea, cursor, srcs, eaf);
    if (use_e)
        edge_mlp_kernel<<<EE / 8, 256, 0, stream>>>(eaf, We, be, eprec);

    // ping-pong: layer l reads x=buf[l&1]; agg writes U into buf[(l+1)&1];
    // mlp writes its output IN PLACE over U (blocks touch only their own rows).
    ushort_t* xbuf[2] = {xb0, xb1};
    for (int l = 0; l < LL; ++l) {
        ushort_t* xin = xbuf[l & 1];
        ushort_t* Ub  = xbuf[(l + 1) & 1];
        if (use_e)
            agg_kernel<1><<<2048, 256, 0, stream>>>(off, srcs, eprec, eaf, We, be, xin, Ub);
        else
            agg_kernel<0><<<2048, 256, 0, stream>>>(off, srcs, eprec, eaf, We, be, xin, Ub);
        if (l == LL - 1) {
            mlp_kernel<1><<<NN / 64, 512, 0, stream>>>(
                Ub, Wc1 + l * 65536, Wc2 + l * 65536, b1 + l * HDIM, b2 + l * HDIM,
                lng + l * HDIM, lnb + l * HDIM, xin, Ub, x);
        } else {
            mlp_kernel<0><<<NN / 64, 512, 0, stream>>>(
                Ub, Wc1 + l * 65536, Wc2 + l * 65536, b1 + l * HDIM, b2 + l * HDIM,
                lng + l * HDIM, lnb + l * HDIM, xin, Ub, nullptr);
        }
    }
}